// Round 6
// baseline (1042.736 us; speedup 1.0000x reference)
//
#include <hip/hip_runtime.h>

#define N_NODES 25000
#define E_EDGES 400000
#define KM 200     // message channels
#define RS 224     // fused row stride (floats): 200 A/B + up to 20 x + pad (896 B)

// ---------------- sort-by-dst (CSR build) ----------------

__global__ void hist_kernel(const int* __restrict__ edges, int* __restrict__ hist) {
  int e = blockIdx.x * blockDim.x + threadIdx.x;
  if (e < E_EDGES) atomicAdd(&hist[edges[E_EDGES + e]], 1);
}

__global__ void scan_kernel(const int* __restrict__ hist, int* __restrict__ off,
                            int* __restrict__ cursor) {
  __shared__ int sums[1024];
  const int CH = (N_NODES + 1023) / 1024;  // 25
  int tid = threadIdx.x;
  int base = tid * CH;
  int s = 0;
  for (int i = 0; i < CH; i++) {
    int idx = base + i;
    if (idx < N_NODES) s += hist[idx];
  }
  sums[tid] = s;
  __syncthreads();
  for (int d = 1; d < 1024; d <<= 1) {
    int v = (tid >= d) ? sums[tid - d] : 0;
    __syncthreads();
    sums[tid] += v;
    __syncthreads();
  }
  int run = (tid == 0) ? 0 : sums[tid - 1];
  for (int i = 0; i < CH; i++) {
    int idx = base + i;
    if (idx < N_NODES) {
      off[idx] = run;
      cursor[idx] = run;
      run += hist[idx];
    }
  }
  if (tid == 1023) off[N_NODES] = run;  // == E
}

__global__ void scatter_kernel(const int* __restrict__ edges, int* __restrict__ cursor,
                               int* __restrict__ srcS, int* __restrict__ dstS) {
  int e = blockIdx.x * blockDim.x + threadIdx.x;
  if (e < E_EDGES) {
    int s = edges[e];
    int d = edges[E_EDGES + e];
    int pos = atomicAdd(&cursor[d], 1);
    srcS[pos] = s;
    dstS[pos] = d;
  }
}

// ---------------- per-layer kernels ----------------

// Node prep: xv = relu?(xin)
//   A2[n] = [ xv@Wm1_top + bm1 (200) | xv (CIN) | pad ]   (stride RS floats)
//   B2[n] = [ xv@Wm1_bot       (200) | xv (CIN) | pad ]
//   xr[n][c] = xv  (compact copy for aggfin)
template <int CIN>
__global__ void prep_kernel(const float* __restrict__ xin, int do_relu,
                            const float* __restrict__ Wm1, const float* __restrict__ bm1,
                            float* __restrict__ A2, float* __restrict__ B2,
                            float* __restrict__ xr) {
  const int NT = 8;
  int k = threadIdx.x;  // 0..255
  float wa[CIN], wb[CIN];
  float bm = 0.f;
  if (k < KM) {
    bm = bm1[k];
#pragma unroll
    for (int c = 0; c < CIN; c++) {
      wa[c] = Wm1[c * KM + k];
      wb[c] = Wm1[(CIN + c) * KM + k];
    }
  }
  int n0 = blockIdx.x * NT;
  for (int i = 0; i < NT; i++) {
    int n = n0 + i;
    float xv[CIN];
#pragma unroll
    for (int c = 0; c < CIN; c++) {
      float v = xin[n * CIN + c];
      xv[c] = do_relu ? fmaxf(v, 0.f) : v;
    }
    size_t row = (size_t)n * RS;
    if (k < CIN) {
      xr[n * CIN + k] = xv[k];
      A2[row + KM + k] = xv[k];
      B2[row + KM + k] = xv[k];
    }
    if (k < KM) {
      float a = bm, b = 0.f;
#pragma unroll
      for (int c = 0; c < CIN; c++) {
        a += xv[c] * wa[c];
        b += xv[c] * wb[c];
      }
      A2[row + k] = a;
      B2[row + k] = b;
    }
  }
}

// Edge kernel: one thread per (dst-sorted) edge. Per-wave LDS staging of B-rows:
// each 32-float chunk of each edge's B-row is cooperatively gathered so every
// cache line is fetched exactly once (R1-R5 had ~4.5x L1-thrash over-fetch).
// A-rows stay direct (dst-sorted => ~16-lane same-address broadcast).
// lds layout [wave][quarter][edge] (float4): both write (addr=16*((q*64)+e)) and
// read (addr=16*lane within quarter-plane) are the canonical conflict-free
// stride-16 pattern. No __syncthreads: per-wave buffer, same-wave LDS in-order.
template <int CIN>
__global__ void __launch_bounds__(256) edge_kernel(
    const int* __restrict__ srcS, const int* __restrict__ dstS,
    const float* __restrict__ A2, const float* __restrict__ B2,
    const float* __restrict__ Wm2, const float* __restrict__ bm2,
    float* __restrict__ gd) {
  __shared__ float4 lds[4][8][64];  // 32 KB/block
  int tid = threadIdx.x;
  int wave = tid >> 6;
  int lane = tid & 63;
  int ebase = blockIdx.x * 256 + wave * 64;
  int e0 = ebase + lane;
  bool valid = (e0 < E_EDGES);
  int e = valid ? e0 : (E_EDGES - 1);
  int dst = dstS[e];
  int src = srcS[e];
  const float* Ar = A2 + (size_t)dst * RS;
  const float* Br = B2 + (size_t)src * RS;

  // loader role: this lane stages quarter lq (4 floats) of edges le+8j
  int lq = lane >> 3;  // 0..7
  int le = lane & 7;   // 0..7
  const float* rb[8];
#pragma unroll
  for (int j = 0; j < 8; j++) {
    int ee = ebase + le + 8 * j;
    if (ee >= E_EDGES) ee = E_EDGES - 1;
    rb[j] = B2 + (size_t)srcS[ee] * RS + 4 * lq;
  }

  float gate[CIN];
#pragma unroll
  for (int c = 0; c < CIN; c++) gate[c] = bm2[c];

#pragma unroll 1
  for (int kc = 0; kc < 192; kc += 32) {
    // cooperative stage: 64 float4 per 8-lane group; each line fetched once
#pragma unroll
    for (int j = 0; j < 8; j++) {
      lds[wave][lq][le + 8 * j] = *(const float4*)(rb[j] + kc);
    }
    __builtin_amdgcn_sched_barrier(0);  // pin write-before-read program order
#pragma unroll
    for (int q = 0; q < 8; q++) {
      float4 b = lds[wave][q][lane];
      float4 a = *(const float4*)(Ar + kc + 4 * q);
      float h0 = fmaxf(a.x + b.x, 0.f);
      float h1 = fmaxf(a.y + b.y, 0.f);
      float h2 = fmaxf(a.z + b.z, 0.f);
      float h3 = fmaxf(a.w + b.w, 0.f);
      int kb = kc + 4 * q;
#pragma unroll
      for (int c = 0; c < CIN; c++) {
        gate[c] += h0 * Wm2[(kb + 0) * CIN + c] + h1 * Wm2[(kb + 1) * CIN + c] +
                   h2 * Wm2[(kb + 2) * CIN + c] + h3 * Wm2[(kb + 3) * CIN + c];
      }
    }
    __builtin_amdgcn_sched_barrier(0);  // reads done before next chunk's writes
  }
  // tail k = 192..199: direct gather from own row (2 lines)
#pragma unroll
  for (int q = 0; q < 2; q++) {
    float4 b = *(const float4*)(Br + 192 + 4 * q);
    float4 a = *(const float4*)(Ar + 192 + 4 * q);
    float h0 = fmaxf(a.x + b.x, 0.f);
    float h1 = fmaxf(a.y + b.y, 0.f);
    float h2 = fmaxf(a.z + b.z, 0.f);
    float h3 = fmaxf(a.w + b.w, 0.f);
    int kb = 192 + 4 * q;
#pragma unroll
    for (int c = 0; c < CIN; c++) {
      gate[c] += h0 * Wm2[(kb + 0) * CIN + c] + h1 * Wm2[(kb + 1) * CIN + c] +
                 h2 * Wm2[(kb + 2) * CIN + c] + h3 * Wm2[(kb + 3) * CIN + c];
    }
  }

  // x-diff tails (same rows) + coalesced gd stores
  if (!valid) return;
  if constexpr (CIN % 4 == 0) {
#pragma unroll
    for (int q = 0; q < CIN / 4; q++) {
      float4 xa = *(const float4*)(Ar + KM + 4 * q);
      float4 xb = *(const float4*)(Br + KM + 4 * q);
      float xd[4] = {xa.x - xb.x, xa.y - xb.y, xa.z - xb.z, xa.w - xb.w};
#pragma unroll
      for (int j = 0; j < 4; j++) {
        int c = 4 * q + j;
        gd[(size_t)c * E_EDGES + e0] = gate[c] * xd[j];
      }
    }
  } else {
#pragma unroll
    for (int c = 0; c < CIN; c++) {
      gd[(size_t)c * E_EDGES + e0] = gate[c] * (Ar[KM + c] - Br[KM + c]);
    }
  }
}

// aggfin (CIN=1): thread per node; segment-sum gd[0][...] then 20 outputs.
__global__ void aggfin_1_20(const float* __restrict__ gd, const int* __restrict__ off,
                            const float* __restrict__ xr,
                            const float* __restrict__ W1, const float* __restrict__ b1,
                            const float* __restrict__ W2, const float* __restrict__ b2,
                            float* __restrict__ out) {
  int n = blockIdx.x * blockDim.x + threadIdx.x;
  if (n >= N_NODES) return;
  int s = off[n];
  int t = off[n + 1];
  float v = 0.f;
  for (int e = s; e < t; e++) v += gd[e];
  float x = xr[n];
  float deg = (float)(t - s);
#pragma unroll
  for (int o = 0; o < 20; o++) {
    out[n * 20 + o] = b1[o] + deg * b2[o] + v * W2[o] + x * W1[o];
  }
}

// aggfin (CIN=20): 12 nodes/block, thread (g,c): segment-sum channel c of node
// n(g) into LDS, then thread (g,o) computes out[n][o] via 20x(2 FMA).
template <int COUT>
__global__ void __launch_bounds__(256) aggfin_20(
    const float* __restrict__ gd, const int* __restrict__ off,
    const float* __restrict__ xr,
    const float* __restrict__ W1, const float* __restrict__ b1,
    const float* __restrict__ W2, const float* __restrict__ b2,
    float* __restrict__ out) {
  __shared__ float lag[12][21];
  __shared__ float lx[12][21];
  int g = threadIdx.x / 20;
  int c = threadIdx.x - g * 20;
  int n = blockIdx.x * 12 + g;
  bool act = (g < 12) && (n < N_NODES);
  int s = 0, t = 0;
  if (act) {
    s = off[n];
    t = off[n + 1];
    const float* row = gd + (size_t)c * E_EDGES;
    float v = 0.f;
    for (int e = s; e < t; e++) v += row[e];
    lag[g][c] = v;
    lx[g][c] = xr[n * 20 + c];
  }
  __syncthreads();
  if (act && c < COUT) {
    float deg = (float)(t - s);
    float v = b1[c] + deg * b2[c];
#pragma unroll
    for (int cc = 0; cc < 20; cc++) {
      v += lag[g][cc] * W2[cc * COUT + c] + lx[g][cc] * W1[cc * COUT + c];
    }
    out[(size_t)n * COUT + c] = v;
  }
}

// ---------------- launch ----------------

extern "C" void kernel_launch(void* const* d_in, const int* in_sizes, int n_in,
                              void* d_out, int out_size, void* d_ws, size_t ws_size,
                              hipStream_t stream) {
  const float* features = (const float*)d_in[0];
  const int* edges = (const int*)d_in[1];
  // d_in[2] = weights (unused by reference)

  const float *dW1 = (const float*)d_in[3], *db1 = (const float*)d_in[4],
              *dWm1 = (const float*)d_in[5], *dbm1 = (const float*)d_in[6],
              *dWm2 = (const float*)d_in[7], *dbm2 = (const float*)d_in[8],
              *dW2 = (const float*)d_in[9], *db2 = (const float*)d_in[10];
  const float *hW1 = (const float*)d_in[11], *hb1 = (const float*)d_in[12],
              *hWm1 = (const float*)d_in[13], *hbm1 = (const float*)d_in[14],
              *hWm2 = (const float*)d_in[15], *hbm2 = (const float*)d_in[16],
              *hW2 = (const float*)d_in[17], *hb2 = (const float*)d_in[18];
  const float *oW1 = (const float*)d_in[19], *ob1 = (const float*)d_in[20],
              *oWm1 = (const float*)d_in[21], *obm1 = (const float*)d_in[22],
              *oWm2 = (const float*)d_in[23], *obm2 = (const float*)d_in[24],
              *oW2 = (const float*)d_in[25], *ob2 = (const float*)d_in[26];

  // workspace layout (float units)
  float* fws = (float*)d_ws;
  size_t o = 0;
  float* A2 = fws + o;   o += (size_t)N_NODES * RS;   // 5.6M
  float* B2 = fws + o;   o += (size_t)N_NODES * RS;   // 5.6M
  float* gd = fws + o;   o += (size_t)20 * E_EDGES;   // 8.0M
  float* xr = fws + o;   o += (size_t)N_NODES * 20;
  float* acc1 = fws + o; o += (size_t)N_NODES * 20;
  float* acc2 = fws + o; o += (size_t)N_NODES * 20;
  int* ip = (int*)(fws + o);
  int* hist = ip;   ip += N_NODES;
  int* off = ip;    ip += N_NODES + 4;
  int* cursor = ip; ip += N_NODES;
  int* srcS = ip;   ip += E_EDGES;
  int* dstS = ip;   ip += E_EDGES;

  const int B256 = 256;
  const int EDGE_G = (E_EDGES + B256 - 1) / B256;  // 1563
  const int NODE_G = (N_NODES + B256 - 1) / B256;
  const int PREP_G = N_NODES / 8;  // 3125, exact
  const int AGGF_G = (N_NODES + 11) / 12;  // 2084

  // build dst-sorted edge list + CSR offsets (recomputed every launch)
  hipMemsetAsync(hist, 0, N_NODES * sizeof(int), stream);
  hist_kernel<<<EDGE_G, B256, 0, stream>>>(edges, hist);
  scan_kernel<<<1, 1024, 0, stream>>>(hist, off, cursor);
  scatter_kernel<<<EDGE_G, B256, 0, stream>>>(edges, cursor, srcS, dstS);

  // layer d: 1 -> 20
  prep_kernel<1><<<PREP_G, B256, 0, stream>>>(features, 0, dWm1, dbm1, A2, B2, xr);
  edge_kernel<1><<<EDGE_G, B256, 0, stream>>>(srcS, dstS, A2, B2, dWm2, dbm2, gd);
  aggfin_1_20<<<NODE_G, B256, 0, stream>>>(gd, off, xr, dW1, db1, dW2, db2, acc1);

  // 3 hidden layers: 20 -> 20 (relu applied to input inside prep)
  float* cur = acc1;
  float* nxt = acc2;
  for (int i = 0; i < 3; i++) {
    prep_kernel<20><<<PREP_G, B256, 0, stream>>>(cur, 1, hWm1, hbm1, A2, B2, xr);
    edge_kernel<20><<<EDGE_G, B256, 0, stream>>>(srcS, dstS, A2, B2, hWm2, hbm2, gd);
    aggfin_20<20><<<AGGF_G, B256, 0, stream>>>(gd, off, xr, hW1, hb1, hW2, hb2, nxt);
    float* tmp = cur; cur = nxt; nxt = tmp;
  }

  // output layer: 20 -> 1 (no trailing relu)
  prep_kernel<20><<<PREP_G, B256, 0, stream>>>(cur, 1, oWm1, obm1, A2, B2, xr);
  edge_kernel<20><<<EDGE_G, B256, 0, stream>>>(srcS, dstS, A2, B2, oWm2, obm2, gd);
  aggfin_20<1><<<AGGF_G, B256, 0, stream>>>(gd, off, xr, oW1, ob1, oW2, ob2,
                                            (float*)d_out);
}

// Round 8
// 942.012 us; speedup vs baseline: 1.1069x; 1.1069x over previous
//
#include <hip/hip_runtime.h>

#define N_NODES 25000
#define E_EDGES 400000
#define KM 200     // message channels
#define RS 224     // fused row stride (floats): 200 A/B + up to 20 x + pad (896 B)

typedef float vfloat4 __attribute__((ext_vector_type(4)));  // for nontemporal builtins

// ---------------- sort-by-dst (CSR build) ----------------

__global__ void hist_kernel(const int* __restrict__ edges, int* __restrict__ hist) {
  int e = blockIdx.x * blockDim.x + threadIdx.x;
  if (e < E_EDGES) atomicAdd(&hist[edges[E_EDGES + e]], 1);
}

__global__ void scan_kernel(const int* __restrict__ hist, int* __restrict__ off,
                            int* __restrict__ cursor) {
  __shared__ int sums[1024];
  const int CH = (N_NODES + 1023) / 1024;  // 25
  int tid = threadIdx.x;
  int base = tid * CH;
  int s = 0;
  for (int i = 0; i < CH; i++) {
    int idx = base + i;
    if (idx < N_NODES) s += hist[idx];
  }
  sums[tid] = s;
  __syncthreads();
  for (int d = 1; d < 1024; d <<= 1) {
    int v = (tid >= d) ? sums[tid - d] : 0;
    __syncthreads();
    sums[tid] += v;
    __syncthreads();
  }
  int run = (tid == 0) ? 0 : sums[tid - 1];
  for (int i = 0; i < CH; i++) {
    int idx = base + i;
    if (idx < N_NODES) {
      off[idx] = run;
      cursor[idx] = run;
      run += hist[idx];
    }
  }
  if (tid == 1023) off[N_NODES] = run;  // == E
}

__global__ void scatter_kernel(const int* __restrict__ edges, int* __restrict__ cursor,
                               int* __restrict__ srcS, int* __restrict__ dstS) {
  int e = blockIdx.x * blockDim.x + threadIdx.x;
  if (e < E_EDGES) {
    int s = edges[e];
    int d = edges[E_EDGES + e];
    int pos = atomicAdd(&cursor[d], 1);
    srcS[pos] = s;
    dstS[pos] = d;
  }
}

// ---------------- per-layer kernels ----------------

// Node prep: xv = relu?(xin)
//   A2[n] = [ xv@Wm1_top + bm1 (200) | xv (CIN) | pad ]   (stride RS floats)
//   B2[n] = [ xv@Wm1_bot       (200) | xv (CIN) | pad ]
//   xr[n][c] = xv  (compact copy for aggfin)
template <int CIN>
__global__ void prep_kernel(const float* __restrict__ xin, int do_relu,
                            const float* __restrict__ Wm1, const float* __restrict__ bm1,
                            float* __restrict__ A2, float* __restrict__ B2,
                            float* __restrict__ xr) {
  const int NT = 8;
  int k = threadIdx.x;  // 0..255
  float wa[CIN], wb[CIN];
  float bm = 0.f;
  if (k < KM) {
    bm = bm1[k];
#pragma unroll
    for (int c = 0; c < CIN; c++) {
      wa[c] = Wm1[c * KM + k];
      wb[c] = Wm1[(CIN + c) * KM + k];
    }
  }
  int n0 = blockIdx.x * NT;
  for (int i = 0; i < NT; i++) {
    int n = n0 + i;
    float xv[CIN];
#pragma unroll
    for (int c = 0; c < CIN; c++) {
      float v = xin[n * CIN + c];
      xv[c] = do_relu ? fmaxf(v, 0.f) : v;
    }
    size_t row = (size_t)n * RS;
    if (k < CIN) {
      xr[n * CIN + k] = xv[k];
      A2[row + KM + k] = xv[k];
      B2[row + KM + k] = xv[k];
    }
    if (k < KM) {
      float a = bm, b = 0.f;
#pragma unroll
      for (int c = 0; c < CIN; c++) {
        a += xv[c] * wa[c];
        b += xv[c] * wb[c];
      }
      A2[row + k] = a;
      B2[row + k] = b;
    }
  }
}

// Edge kernel: one thread per (dst-sorted) edge (R1 shape — best measured).
// h_k = relu(A2[dst][k] + B2[src][k]); gate = h@Wm2 + bm2;
// gd layout [e][c]: 5 contiguous nontemporal float4 stores per edge (CIN=20),
// so aggfin reads each node's segment as one contiguous stream.
template <int CIN>
__global__ void __launch_bounds__(256) edge_kernel(
    const int* __restrict__ srcS, const int* __restrict__ dstS,
    const float* __restrict__ A2, const float* __restrict__ B2,
    const float* __restrict__ Wm2, const float* __restrict__ bm2,
    float* __restrict__ gd) {
  int e = blockIdx.x * 256 + threadIdx.x;
  if (e >= E_EDGES) return;
  int src = srcS[e];
  int dst = dstS[e];
  const float* Ar = A2 + (size_t)dst * RS;
  const float* Br = B2 + (size_t)src * RS;
  float gate[CIN];
#pragma unroll
  for (int c = 0; c < CIN; c++) gate[c] = bm2[c];
#pragma unroll 2
  for (int k = 0; k < KM; k += 4) {
    float4 a4 = *(const float4*)(Ar + k);
    float4 b4 = *(const float4*)(Br + k);
    float h0 = fmaxf(a4.x + b4.x, 0.f);
    float h1 = fmaxf(a4.y + b4.y, 0.f);
    float h2 = fmaxf(a4.z + b4.z, 0.f);
    float h3 = fmaxf(a4.w + b4.w, 0.f);
#pragma unroll
    for (int c = 0; c < CIN; c++) {
      gate[c] += h0 * Wm2[(k + 0) * CIN + c] + h1 * Wm2[(k + 1) * CIN + c] +
                 h2 * Wm2[(k + 2) * CIN + c] + h3 * Wm2[(k + 3) * CIN + c];
    }
  }
  // x-diff tails (same rows, L1-hot) + per-edge contiguous stores
  if constexpr (CIN == 20) {
    vfloat4* g4 = (vfloat4*)gd + (size_t)e * 5;
#pragma unroll
    for (int q = 0; q < 5; q++) {
      float4 xa = *(const float4*)(Ar + KM + 4 * q);
      float4 xb = *(const float4*)(Br + KM + 4 * q);
      vfloat4 st;
      st.x = gate[4 * q + 0] * (xa.x - xb.x);
      st.y = gate[4 * q + 1] * (xa.y - xb.y);
      st.z = gate[4 * q + 2] * (xa.z - xb.z);
      st.w = gate[4 * q + 3] * (xa.w - xb.w);
      __builtin_nontemporal_store(st, g4 + q);
    }
  } else {
    float xd = Ar[KM] - Br[KM];
    __builtin_nontemporal_store(gate[0] * xd, gd + e);
  }
}

// aggfin (CIN=1): thread per node; segment-sum gd[0][...] then 20 outputs.
__global__ void aggfin_1_20(const float* __restrict__ gd, const int* __restrict__ off,
                            const float* __restrict__ xr,
                            const float* __restrict__ W1, const float* __restrict__ b1,
                            const float* __restrict__ W2, const float* __restrict__ b2,
                            float* __restrict__ out) {
  int n = blockIdx.x * blockDim.x + threadIdx.x;
  if (n >= N_NODES) return;
  int s = off[n];
  int t = off[n + 1];
  float v = 0.f;
  for (int e = s; e < t; e++) v += gd[e];
  float x = xr[n];
  float deg = (float)(t - s);
#pragma unroll
  for (int o = 0; o < 20; o++) {
    out[n * 20 + o] = b1[o] + deg * b2[o] + v * W2[o] + x * W1[o];
  }
}

// aggfin2 (CIN=20): thread per node. gd[e][c] layout -> the node's segment is
// a contiguous (t-s)*80B stream; 5 independent float4 accumulators (MLP=5),
// then the 20->COUT epilogue in-thread.
template <int COUT>
__global__ void __launch_bounds__(64) aggfin2(
    const float* __restrict__ gd, const int* __restrict__ off,
    const float* __restrict__ xr,
    const float* __restrict__ W1, const float* __restrict__ b1,
    const float* __restrict__ W2, const float* __restrict__ b2,
    float* __restrict__ out) {
  int n = blockIdx.x * blockDim.x + threadIdx.x;
  if (n >= N_NODES) return;
  int s = off[n];
  int t = off[n + 1];
  float ag[20];
#pragma unroll
  for (int c = 0; c < 20; c++) ag[c] = 0.f;
  const float4* g4 = (const float4*)gd;
  for (int e = s; e < t; e++) {
#pragma unroll
    for (int j = 0; j < 5; j++) {
      float4 v = g4[(size_t)e * 5 + j];
      ag[4 * j + 0] += v.x;
      ag[4 * j + 1] += v.y;
      ag[4 * j + 2] += v.z;
      ag[4 * j + 3] += v.w;
    }
  }
  float xv[20];
  const float4* x4 = (const float4*)(xr + (size_t)n * 20);
#pragma unroll
  for (int j = 0; j < 5; j++) {
    float4 v = x4[j];
    xv[4 * j + 0] = v.x;
    xv[4 * j + 1] = v.y;
    xv[4 * j + 2] = v.z;
    xv[4 * j + 3] = v.w;
  }
  float deg = (float)(t - s);
#pragma unroll
  for (int o = 0; o < COUT; o++) {
    float v = b1[o] + deg * b2[o];
#pragma unroll
    for (int c = 0; c < 20; c++) {
      v += ag[c] * W2[c * COUT + o] + xv[c] * W1[c * COUT + o];
    }
    out[(size_t)n * COUT + o] = v;
  }
}

// ---------------- launch ----------------

extern "C" void kernel_launch(void* const* d_in, const int* in_sizes, int n_in,
                              void* d_out, int out_size, void* d_ws, size_t ws_size,
                              hipStream_t stream) {
  const float* features = (const float*)d_in[0];
  const int* edges = (const int*)d_in[1];
  // d_in[2] = weights (unused by reference)

  const float *dW1 = (const float*)d_in[3], *db1 = (const float*)d_in[4],
              *dWm1 = (const float*)d_in[5], *dbm1 = (const float*)d_in[6],
              *dWm2 = (const float*)d_in[7], *dbm2 = (const float*)d_in[8],
              *dW2 = (const float*)d_in[9], *db2 = (const float*)d_in[10];
  const float *hW1 = (const float*)d_in[11], *hb1 = (const float*)d_in[12],
              *hWm1 = (const float*)d_in[13], *hbm1 = (const float*)d_in[14],
              *hWm2 = (const float*)d_in[15], *hbm2 = (const float*)d_in[16],
              *hW2 = (const float*)d_in[17], *hb2 = (const float*)d_in[18];
  const float *oW1 = (const float*)d_in[19], *ob1 = (const float*)d_in[20],
              *oWm1 = (const float*)d_in[21], *obm1 = (const float*)d_in[22],
              *oWm2 = (const float*)d_in[23], *obm2 = (const float*)d_in[24],
              *oW2 = (const float*)d_in[25], *ob2 = (const float*)d_in[26];

  // workspace layout (float units)
  float* fws = (float*)d_ws;
  size_t o = 0;
  float* A2 = fws + o;   o += (size_t)N_NODES * RS;   // 5.6M
  float* B2 = fws + o;   o += (size_t)N_NODES * RS;   // 5.6M
  float* gd = fws + o;   o += (size_t)20 * E_EDGES;   // 8.0M ([e][c], e*5 float4)
  float* xr = fws + o;   o += (size_t)N_NODES * 20;
  float* acc1 = fws + o; o += (size_t)N_NODES * 20;
  float* acc2 = fws + o; o += (size_t)N_NODES * 20;
  int* ip = (int*)(fws + o);
  int* hist = ip;   ip += N_NODES;
  int* off = ip;    ip += N_NODES + 4;
  int* cursor = ip; ip += N_NODES;
  int* srcS = ip;   ip += E_EDGES;
  int* dstS = ip;   ip += E_EDGES;

  const int B256 = 256;
  const int EDGE_G = (E_EDGES + B256 - 1) / B256;  // 1563
  const int NODE_G = (N_NODES + B256 - 1) / B256;
  const int PREP_G = N_NODES / 8;  // 3125, exact
  const int AGGF_G = (N_NODES + 63) / 64;  // 391 (64-thread blocks spread CUs)

  // build dst-sorted edge list + CSR offsets (recomputed every launch)
  (void)hipMemsetAsync(hist, 0, N_NODES * sizeof(int), stream);
  hist_kernel<<<EDGE_G, B256, 0, stream>>>(edges, hist);
  scan_kernel<<<1, 1024, 0, stream>>>(hist, off, cursor);
  scatter_kernel<<<EDGE_G, B256, 0, stream>>>(edges, cursor, srcS, dstS);

  // layer d: 1 -> 20
  prep_kernel<1><<<PREP_G, B256, 0, stream>>>(features, 0, dWm1, dbm1, A2, B2, xr);
  edge_kernel<1><<<EDGE_G, B256, 0, stream>>>(srcS, dstS, A2, B2, dWm2, dbm2, gd);
  aggfin_1_20<<<NODE_G, B256, 0, stream>>>(gd, off, xr, dW1, db1, dW2, db2, acc1);

  // 3 hidden layers: 20 -> 20 (relu applied to input inside prep)
  float* cur = acc1;
  float* nxt = acc2;
  for (int i = 0; i < 3; i++) {
    prep_kernel<20><<<PREP_G, B256, 0, stream>>>(cur, 1, hWm1, hbm1, A2, B2, xr);
    edge_kernel<20><<<EDGE_G, B256, 0, stream>>>(srcS, dstS, A2, B2, hWm2, hbm2, gd);
    aggfin2<20><<<AGGF_G, 64, 0, stream>>>(gd, off, xr, hW1, hb1, hW2, hb2, nxt);
    float* tmp = cur; cur = nxt; nxt = tmp;
  }

  // output layer: 20 -> 1 (no trailing relu)
  prep_kernel<20><<<PREP_G, B256, 0, stream>>>(cur, 1, oWm1, obm1, A2, B2, xr);
  edge_kernel<20><<<EDGE_G, B256, 0, stream>>>(srcS, dstS, A2, B2, oWm2, obm2, gd);
  aggfin2<1><<<AGGF_G, 64, 0, stream>>>(gd, off, xr, oW1, ob1, oW2, ob2,
                                        (float*)d_out);
}

// Round 9
// 911.300 us; speedup vs baseline: 1.1442x; 1.0337x over previous
//
#include <hip/hip_runtime.h>

#define N_NODES 25000
#define E_EDGES 400000
#define KM 200     // message channels
#define RS 224     // fused row stride (floats): 200 A/B + up to 20 x + pad (896 B)

typedef float vfloat4 __attribute__((ext_vector_type(4)));  // for nontemporal builtins

// ---------------- sort-by-dst (CSR build) ----------------

__global__ void hist_kernel(const int* __restrict__ edges, int* __restrict__ hist) {
  int e = blockIdx.x * blockDim.x + threadIdx.x;
  if (e < E_EDGES) atomicAdd(&hist[edges[E_EDGES + e]], 1);
}

__global__ void scan_kernel(const int* __restrict__ hist, int* __restrict__ off,
                            int* __restrict__ cursor) {
  __shared__ int sums[1024];
  const int CH = (N_NODES + 1023) / 1024;  // 25
  int tid = threadIdx.x;
  int base = tid * CH;
  int s = 0;
  for (int i = 0; i < CH; i++) {
    int idx = base + i;
    if (idx < N_NODES) s += hist[idx];
  }
  sums[tid] = s;
  __syncthreads();
  for (int d = 1; d < 1024; d <<= 1) {
    int v = (tid >= d) ? sums[tid - d] : 0;
    __syncthreads();
    sums[tid] += v;
    __syncthreads();
  }
  int run = (tid == 0) ? 0 : sums[tid - 1];
  for (int i = 0; i < CH; i++) {
    int idx = base + i;
    if (idx < N_NODES) {
      off[idx] = run;
      cursor[idx] = run;
      run += hist[idx];
    }
  }
  if (tid == 1023) off[N_NODES] = run;  // == E
}

__global__ void scatter_kernel(const int* __restrict__ edges, int* __restrict__ cursor,
                               int* __restrict__ srcS, int* __restrict__ dstS) {
  int e = blockIdx.x * blockDim.x + threadIdx.x;
  if (e < E_EDGES) {
    int s = edges[e];
    int d = edges[E_EDGES + e];
    int pos = atomicAdd(&cursor[d], 1);
    srcS[pos] = s;
    dstS[pos] = d;
  }
}

// ---------------- per-layer kernels ----------------

// Node prep: xv = relu?(xin)
//   A2[n] = [ xv@Wm1_top + bm1 (200) | xv (CIN) | pad ]   (stride RS floats)
//   B2[n] = [ xv@Wm1_bot       (200) | xv (CIN) | pad ]
//   xr[n][c] = xv  (compact copy for fin)
template <int CIN>
__global__ void prep_kernel(const float* __restrict__ xin, int do_relu,
                            const float* __restrict__ Wm1, const float* __restrict__ bm1,
                            float* __restrict__ A2, float* __restrict__ B2,
                            float* __restrict__ xr) {
  const int NT = 8;
  int k = threadIdx.x;  // 0..255
  float wa[CIN], wb[CIN];
  float bm = 0.f;
  if (k < KM) {
    bm = bm1[k];
#pragma unroll
    for (int c = 0; c < CIN; c++) {
      wa[c] = Wm1[c * KM + k];
      wb[c] = Wm1[(CIN + c) * KM + k];
    }
  }
  int n0 = blockIdx.x * NT;
  for (int i = 0; i < NT; i++) {
    int n = n0 + i;
    float xv[CIN];
#pragma unroll
    for (int c = 0; c < CIN; c++) {
      float v = xin[n * CIN + c];
      xv[c] = do_relu ? fmaxf(v, 0.f) : v;
    }
    size_t row = (size_t)n * RS;
    if (k < CIN) {
      xr[n * CIN + k] = xv[k];
      A2[row + KM + k] = xv[k];
      B2[row + KM + k] = xv[k];
    }
    if (k < KM) {
      float a = bm, b = 0.f;
#pragma unroll
      for (int c = 0; c < CIN; c++) {
        a += xv[c] * wa[c];
        b += xv[c] * wb[c];
      }
      A2[row + k] = a;
      B2[row + k] = b;
    }
  }
}

// Edge kernel: one thread per (dst-sorted) edge (R1 shape — best measured).
// h_k = relu(A2[dst][k] + B2[src][k]); gate = h@Wm2 + bm2;
// gd layout [c][e]: 20 coalesced nontemporal dword stores per edge.
template <int CIN>
__global__ void __launch_bounds__(256) edge_kernel(
    const int* __restrict__ srcS, const int* __restrict__ dstS,
    const float* __restrict__ A2, const float* __restrict__ B2,
    const float* __restrict__ Wm2, const float* __restrict__ bm2,
    float* __restrict__ gd) {
  int e = blockIdx.x * 256 + threadIdx.x;
  if (e >= E_EDGES) return;
  int src = srcS[e];
  int dst = dstS[e];
  const float* Ar = A2 + (size_t)dst * RS;
  const float* Br = B2 + (size_t)src * RS;
  float gate[CIN];
#pragma unroll
  for (int c = 0; c < CIN; c++) gate[c] = bm2[c];
#pragma unroll 2
  for (int k = 0; k < KM; k += 4) {
    float4 a4 = *(const float4*)(Ar + k);
    float4 b4 = *(const float4*)(Br + k);
    float h0 = fmaxf(a4.x + b4.x, 0.f);
    float h1 = fmaxf(a4.y + b4.y, 0.f);
    float h2 = fmaxf(a4.z + b4.z, 0.f);
    float h3 = fmaxf(a4.w + b4.w, 0.f);
#pragma unroll
    for (int c = 0; c < CIN; c++) {
      gate[c] += h0 * Wm2[(k + 0) * CIN + c] + h1 * Wm2[(k + 1) * CIN + c] +
                 h2 * Wm2[(k + 2) * CIN + c] + h3 * Wm2[(k + 3) * CIN + c];
    }
  }
  // x-diff tails (same rows, L1-hot) + coalesced nontemporal stores
  if constexpr (CIN % 4 == 0) {
#pragma unroll
    for (int q = 0; q < CIN / 4; q++) {
      float4 xa = *(const float4*)(Ar + KM + 4 * q);
      float4 xb = *(const float4*)(Br + KM + 4 * q);
      float xd[4] = {xa.x - xb.x, xa.y - xb.y, xa.z - xb.z, xa.w - xb.w};
#pragma unroll
      for (int j = 0; j < 4; j++) {
        int c = 4 * q + j;
        __builtin_nontemporal_store(gate[c] * xd[j], gd + (size_t)c * E_EDGES + e);
      }
    }
  } else {
#pragma unroll
    for (int c = 0; c < CIN; c++) {
      __builtin_nontemporal_store(gate[c] * (Ar[KM + c] - Br[KM + c]),
                                  gd + (size_t)c * E_EDGES + e);
    }
  }
}

// aggfin (CIN=1): thread per node; segment-sum gd[0][...] then 20 outputs.
__global__ void aggfin_1_20(const float* __restrict__ gd, const int* __restrict__ off,
                            const float* __restrict__ xr,
                            const float* __restrict__ W1, const float* __restrict__ b1,
                            const float* __restrict__ W2, const float* __restrict__ b2,
                            float* __restrict__ out) {
  int n = blockIdx.x * blockDim.x + threadIdx.x;
  if (n >= N_NODES) return;
  int s = off[n];
  int t = off[n + 1];
  float v = 0.f;
  for (int e = s; e < t; e++) v += gd[e];
  float x = xr[n];
  float deg = (float)(t - s);
#pragma unroll
  for (int o = 0; o < 20; o++) {
    out[n * 20 + o] = b1[o] + deg * b2[o] + v * W2[o] + x * W1[o];
  }
}

// agg1: thread per (c, n): aggp[n][c] = sum over CSR segment of gd[c][e].
// Lane-adjacent n (same c) -> wave reads adjacent segments: contiguous stream.
__global__ void agg1_kernel(const float* __restrict__ gd, const int* __restrict__ off,
                            float* __restrict__ aggp) {
  int idx = blockIdx.x * blockDim.x + threadIdx.x;
  if (idx >= 20 * N_NODES) return;
  int c = idx / N_NODES;
  int n = idx - c * N_NODES;
  int s = off[n];
  int t = off[n + 1];
  const float* g = gd + (size_t)c * E_EDGES;
  float v = 0.f;
  for (int e = s; e < t; e++) v += g[e];
  aggp[(size_t)n * 20 + c] = v;
}

// fin2: thread per (n, o): out[n][o] = aggp[n]@W2[:,o] + deg*b2[o] + xr[n]@W1[:,o] + b1[o].
// aggp/xr reads broadcast across a node's COUT lanes; W columns coalesced.
template <int COUT>
__global__ void fin2_kernel(const float* __restrict__ aggp, const int* __restrict__ off,
                            const float* __restrict__ xr,
                            const float* __restrict__ W1, const float* __restrict__ b1,
                            const float* __restrict__ W2, const float* __restrict__ b2,
                            float* __restrict__ out) {
  int idx = blockIdx.x * blockDim.x + threadIdx.x;
  if (idx >= N_NODES * COUT) return;
  int n = idx / COUT;
  int o = idx - n * COUT;
  float deg = (float)(off[n + 1] - off[n]);
  float v = b1[o] + deg * b2[o];
  const float* ag = aggp + (size_t)n * 20;
  const float* xv = xr + (size_t)n * 20;
#pragma unroll
  for (int c = 0; c < 20; c++) {
    v += ag[c] * W2[c * COUT + o] + xv[c] * W1[c * COUT + o];
  }
  out[(size_t)n * COUT + o] = v;
}

// ---------------- launch ----------------

extern "C" void kernel_launch(void* const* d_in, const int* in_sizes, int n_in,
                              void* d_out, int out_size, void* d_ws, size_t ws_size,
                              hipStream_t stream) {
  const float* features = (const float*)d_in[0];
  const int* edges = (const int*)d_in[1];
  // d_in[2] = weights (unused by reference)

  const float *dW1 = (const float*)d_in[3], *db1 = (const float*)d_in[4],
              *dWm1 = (const float*)d_in[5], *dbm1 = (const float*)d_in[6],
              *dWm2 = (const float*)d_in[7], *dbm2 = (const float*)d_in[8],
              *dW2 = (const float*)d_in[9], *db2 = (const float*)d_in[10];
  const float *hW1 = (const float*)d_in[11], *hb1 = (const float*)d_in[12],
              *hWm1 = (const float*)d_in[13], *hbm1 = (const float*)d_in[14],
              *hWm2 = (const float*)d_in[15], *hbm2 = (const float*)d_in[16],
              *hW2 = (const float*)d_in[17], *hb2 = (const float*)d_in[18];
  const float *oW1 = (const float*)d_in[19], *ob1 = (const float*)d_in[20],
              *oWm1 = (const float*)d_in[21], *obm1 = (const float*)d_in[22],
              *oWm2 = (const float*)d_in[23], *obm2 = (const float*)d_in[24],
              *oW2 = (const float*)d_in[25], *ob2 = (const float*)d_in[26];

  // workspace layout (float units)
  float* fws = (float*)d_ws;
  size_t o = 0;
  float* A2 = fws + o;   o += (size_t)N_NODES * RS;   // 5.6M
  float* B2 = fws + o;   o += (size_t)N_NODES * RS;   // 5.6M
  float* gd = fws + o;   o += (size_t)20 * E_EDGES;   // 8.0M  ([c][e])
  float* xr = fws + o;   o += (size_t)N_NODES * 20;
  float* aggp = fws + o; o += (size_t)N_NODES * 20;
  float* acc1 = fws + o; o += (size_t)N_NODES * 20;
  float* acc2 = fws + o; o += (size_t)N_NODES * 20;
  int* ip = (int*)(fws + o);
  int* hist = ip;   ip += N_NODES;
  int* off = ip;    ip += N_NODES + 4;
  int* cursor = ip; ip += N_NODES;
  int* srcS = ip;   ip += E_EDGES;
  int* dstS = ip;   ip += E_EDGES;

  const int B256 = 256;
  const int EDGE_G = (E_EDGES + B256 - 1) / B256;  // 1563
  const int NODE_G = (N_NODES + B256 - 1) / B256;
  const int PREP_G = N_NODES / 8;  // 3125, exact
  const int AGG1_G = (20 * N_NODES + B256 - 1) / B256;  // 1954
  const int FIN20_G = (20 * N_NODES + B256 - 1) / B256;
  const int FIN1_G = (N_NODES + B256 - 1) / B256;

  // build dst-sorted edge list + CSR offsets (recomputed every launch)
  (void)hipMemsetAsync(hist, 0, N_NODES * sizeof(int), stream);
  hist_kernel<<<EDGE_G, B256, 0, stream>>>(edges, hist);
  scan_kernel<<<1, 1024, 0, stream>>>(hist, off, cursor);
  scatter_kernel<<<EDGE_G, B256, 0, stream>>>(edges, cursor, srcS, dstS);

  // layer d: 1 -> 20
  prep_kernel<1><<<PREP_G, B256, 0, stream>>>(features, 0, dWm1, dbm1, A2, B2, xr);
  edge_kernel<1><<<EDGE_G, B256, 0, stream>>>(srcS, dstS, A2, B2, dWm2, dbm2, gd);
  aggfin_1_20<<<NODE_G, B256, 0, stream>>>(gd, off, xr, dW1, db1, dW2, db2, acc1);

  // 3 hidden layers: 20 -> 20 (relu applied to input inside prep)
  float* cur = acc1;
  float* nxt = acc2;
  for (int i = 0; i < 3; i++) {
    prep_kernel<20><<<PREP_G, B256, 0, stream>>>(cur, 1, hWm1, hbm1, A2, B2, xr);
    edge_kernel<20><<<EDGE_G, B256, 0, stream>>>(srcS, dstS, A2, B2, hWm2, hbm2, gd);
    agg1_kernel<<<AGG1_G, B256, 0, stream>>>(gd, off, aggp);
    fin2_kernel<20><<<FIN20_G, B256, 0, stream>>>(aggp, off, xr, hW1, hb1, hW2, hb2, nxt);
    float* tmp = cur; cur = nxt; nxt = tmp;
  }

  // output layer: 20 -> 1 (no trailing relu)
  prep_kernel<20><<<PREP_G, B256, 0, stream>>>(cur, 1, oWm1, obm1, A2, B2, xr);
  edge_kernel<20><<<EDGE_G, B256, 0, stream>>>(srcS, dstS, A2, B2, oWm2, obm2, gd);
  agg1_kernel<<<AGG1_G, B256, 0, stream>>>(gd, off, aggp);
  fin2_kernel<1><<<FIN1_G, B256, 0, stream>>>(aggp, off, xr, oW1, ob1, oW2, ob2,
                                              (float*)d_out);
}